// Round 4
// baseline (131.131 us; speedup 1.0000x reference)
//
#include <hip/hip_runtime.h>
#include <math.h>

#define BB 64
#define QQ 600
#define NT 80
#define NC 92
#define SLOTS 10     // ceil(600/64)
#define NTILE 10     // 64-query tiles per batch
#define NTHR 256
#define NWAVE 4
#define MAXROUNDS 16 // Jacobi auction cap
#define STALLCAP 3   // break auction after 3 rounds with no new assignment
#define NCAP 9       // LDS row-cache slots (9*600*4B = 21.6KB <= tile's 23.8KB)
#define SPINCAP (1 << 20)
#define MAGIC 0x5A17C0DE

// ---------------------------------------------------------------------------
// R18 == R17 resubmission (R3 bench failed on container acquire, not kernel:
// no pytest error, no counters; all kernel loops are bounded + hang-guarded).
// R17 (on R16). Measured split R16: Phase A ~25us, auction ~14us, drain ~25us.
//  (1) Phase A: softmax stats parallelized 4-way (wave w owns cols
//      [w*23,w*23+23) of each row); exp(x-m) written back into tile so the
//      cost loop does an LDS read * inv_s instead of 20 expf/thread.
//  (2) Auction rounds: round-versioned colrow keys ((MAXROUNDS-round)<<7|tid;
//      fresh rounds have strictly smaller keys -> stale entries lose atomicMin
//      -> no clear pass). plist/pcnt dropped: wv-strided rebid with FIXED
//      row->wave ownership (i%NWAVE); termination via __syncthreads_count.
//  (3) LDS row cache in dead tile memory (9 rows): auction rebids and drain
//      tree-joins re-read the same contested-cluster C rows; ~500cy L3 global
//      loads -> ~100cy ds_reads on every repeat touch. Auction fills are
//      wave-private (fixed ownership); drain reads after the auction's final
//      barrier; miss path == old global-load behavior (correctness-free).
// Solver math (bids, auction invariants, Dijkstra SAP) unchanged from R16.
// ---------------------------------------------------------------------------

template <int CTRL>
__device__ __forceinline__ int dppi(int x) {
    return __builtin_amdgcn_update_dpp(x, x, CTRL, 0xF, 0xF, false);
}

// full-wave (64-lane) min of u32: 4x row_ror DPP (VALU) + xor16 swizzle + xor32
__device__ __forceinline__ unsigned wave_min_u32(unsigned x) {
    unsigned y;
    y = (unsigned)dppi<0x121>((int)x); x = x < y ? x : y;   // ror1
    y = (unsigned)dppi<0x122>((int)x); x = x < y ? x : y;   // ror2
    y = (unsigned)dppi<0x124>((int)x); x = x < y ? x : y;   // ror4
    y = (unsigned)dppi<0x128>((int)x); x = x < y ? x : y;   // ror8 -> row(16) min
    y = (unsigned)__builtin_amdgcn_ds_swizzle((int)x, 0x401F); x = x < y ? x : y; // xor16
    y = (unsigned)__shfl_xor((int)x, 32); x = x < y ? x : y;                      // xor32
    return x;
}

__device__ __forceinline__ unsigned long long u64min(unsigned long long a,
                                                     unsigned long long b) {
    return a < b ? a : b;
}

// full-wave min of u64 (two 32-bit halves per cross-lane move)
__device__ __forceinline__ unsigned long long wave_min_u64(unsigned long long x) {
    union U { unsigned long long v; int i[2]; };
    U c, o; c.v = x;
    o.i[0] = dppi<0x121>(c.i[0]); o.i[1] = dppi<0x121>(c.i[1]); c.v = u64min(c.v, o.v);
    o.i[0] = dppi<0x122>(c.i[0]); o.i[1] = dppi<0x122>(c.i[1]); c.v = u64min(c.v, o.v);
    o.i[0] = dppi<0x124>(c.i[0]); o.i[1] = dppi<0x124>(c.i[1]); c.v = u64min(c.v, o.v);
    o.i[0] = dppi<0x128>(c.i[0]); o.i[1] = dppi<0x128>(c.i[1]); c.v = u64min(c.v, o.v);
    o.i[0] = __builtin_amdgcn_ds_swizzle(c.i[0], 0x401F);
    o.i[1] = __builtin_amdgcn_ds_swizzle(c.i[1], 0x401F); c.v = u64min(c.v, o.v);
    o.i[0] = __shfl_xor(c.i[0], 32);
    o.i[1] = __shfl_xor(c.i[1], 32);                       c.v = u64min(c.v, o.v);
    return c.v;
}

// order-preserving bijections float<->u32, double<->u64 (no NaNs in data)
__device__ __forceinline__ unsigned f32_key(float f) {
    unsigned b = __float_as_uint(f);
    return b ^ ((unsigned)((int)b >> 31) | 0x80000000u);
}
__device__ __forceinline__ float key_f32(unsigned k) {
    unsigned b = (k & 0x80000000u) ? (k ^ 0x80000000u) : ~k;
    return __uint_as_float(b);
}
__device__ __forceinline__ unsigned long long f64_key(double d) {
    unsigned long long b = (unsigned long long)__double_as_longlong(d);
    return b ^ ((unsigned long long)((long long)b >> 63) | 0x8000000000000000ULL);
}
__device__ __forceinline__ double key_f64(unsigned long long k) {
    unsigned long long b = (k & 0x8000000000000000ULL) ? (k ^ 0x8000000000000000ULL) : ~k;
    return __longlong_as_double((long long)b);
}

__global__ __launch_bounds__(256) void matcher_kernel(
    const float* __restrict__ logits,   // (B,Q,NC)
    const float* __restrict__ pboxes,   // (B,Q,4)
    const int*   __restrict__ tlabels,  // (B,NT)
    const float* __restrict__ tboxes,   // (B,NT,4)
    float* __restrict__ cost,           // (B,NT,QQ) ws
    float* __restrict__ pm1,            // (B,NT,NTILE) ws
    float* __restrict__ pm2,            // (B,NT,NTILE) ws
    int*   __restrict__ pmj,            // (B,NT,NTILE) ws
    int*   __restrict__ done,           // (B*16) ws slots, NO init needed
    int* __restrict__ rows_out,         // (B,NT)
    int* __restrict__ cols_out)         // (B,NT)
{
    __shared__ float tile[64 * 93];     // Phase A: exp rows; solver: row cache
    __shared__ float s_pm[4 * 64], s_ps[4 * 64];
    __shared__ float s_tb[NT * 4];
    __shared__ int   s_tl[NT];
    // solver state (tix==0 block only)
    __shared__ double vA[QQ];
    __shared__ double u[NT];
    __shared__ double bidm1[NT], bidm2[NT];
    __shared__ int    bidj[NT], bidver[NT];
    __shared__ int    pA[QQ];
    __shared__ int    verA[QQ];
    __shared__ int    colrow[QQ];
    __shared__ int    assigned[NT];
    __shared__ int    wayA[QQ];
    __shared__ int    c4r[NT];
    __shared__ int    djkA[NT];
    __shared__ int    cslot[NT];        // row -> cache slot (-1 = not cached)
    __shared__ int    ncache;

    const int g   = blockIdx.x;
    const int b   = g / NTILE;
    const int tix = g % NTILE;
    const int tid = threadIdx.x;
    const int qq  = tid & 63;
    const int wv  = tid >> 6;           // 0..3
    const float* C = cost + (size_t)b * NT * QQ;
    float* const cacheF = tile;         // row cache overlays dead tile memory

    // ================= Phase A: cost tile + partials =======================
    {
        const int q0 = tix * 64;
        const int nq = min(64, QQ - q0);   // 24 for the last tile
        const float* src = logits + ((size_t)b * QQ + q0) * NC;
        for (int idx = tid; idx < nq * NC; idx += 256) {
            const int r = idx / NC;
            tile[r * 93 + (idx - r * NC)] = src[idx];
        }
        for (int i = tid; i < NT * 4; i += 256) s_tb[i] = tboxes[b * NT * 4 + i];
        for (int i = tid; i < NT;     i += 256) s_tl[i] = tlabels[b * NT + i];
        __syncthreads();

        // R17: 4-way parallel softmax stats; wave w owns cols [w*23, w*23+23).
        // Rows >= nq produce garbage stats (tile uninitialized) — never read.
        {
            const int c0 = wv * 23;
            const float* r = &tile[qq * 93];
            float pm = r[c0];
            #pragma unroll 11
            for (int c = 1; c < 23; ++c) pm = fmaxf(pm, r[c0 + c]);
            s_pm[wv * 64 + qq] = pm;
        }
        __syncthreads();
        {
            const int c0 = wv * 23;
            float* r = &tile[qq * 93];
            const float m = fmaxf(fmaxf(s_pm[qq], s_pm[64 + qq]),
                                  fmaxf(s_pm[128 + qq], s_pm[192 + qq]));
            float sum = 0.f;
            #pragma unroll 11
            for (int c = 0; c < 23; ++c) {
                const float e = expf(r[c0 + c] - m);
                r[c0 + c] = e;                  // exp written back into tile
                sum += e;
            }
            s_ps[wv * 64 + qq] = sum;
        }
        __syncthreads();

        const bool valid = qq < nq;
        float px1 = 0.f, py1 = 0.f, px2 = 0.f, py2 = 0.f, pa = 0.f, inv_s = 1.f;
        if (valid) {
            const float* pb = pboxes + ((size_t)b * QQ + q0 + qq) * 4;
            px1 = pb[0]; py1 = pb[1]; px2 = pb[2]; py2 = pb[3];
            pa  = (px2 - px1) * (py2 - py1);
            const float s = (s_ps[qq] + s_ps[64 + qq]) + (s_ps[128 + qq] + s_ps[192 + qq]);
            inv_s = 1.f / s;
        }
        float* crow = cost + (size_t)b * NT * QQ + q0 + qq;

        for (int tt = 0; tt < 20; ++tt) {
            const int t = wv * 20 + tt;
            float costv = INFINITY;
            if (valid) {
                const int lbl = s_tl[t];
                const float cc = -(tile[qq * 93 + lbl] * inv_s);  // exp precomputed
                const float tx1 = s_tb[t*4+0], ty1 = s_tb[t*4+1];
                const float tx2 = s_tb[t*4+2], ty2 = s_tb[t*4+3];
                const float cb = fabsf(px1-tx1) + fabsf(py1-ty1)
                               + fabsf(px2-tx2) + fabsf(py2-ty2);
                const float ta = (tx2 - tx1) * (ty2 - ty1);
                const float iw = fmaxf(fminf(px2, tx2) - fmaxf(px1, tx1), 0.f);
                const float ih = fmaxf(fminf(py2, ty2) - fmaxf(py1, ty1), 0.f);
                const float inter = iw * ih;
                const float uni   = pa + ta - inter;
                const float iou   = inter / uni;
                const float cw = fmaxf(fmaxf(px2, tx2) - fminf(px1, tx1), 0.f);
                const float ch = fmaxf(fmaxf(py2, ty2) - fminf(py1, ty1), 0.f);
                const float ac = cw * ch;
                const float giou = iou - (ac - uni) / ac;
                costv = (1.0f * cc + 5.0f * cb) + 2.0f * (-giou);
                crow[(size_t)t * QQ] = costv;
            }
            // DPP min-reduce on sortable keys + ballot argmin (R16-validated)
            const unsigned key  = f32_key(costv);          // INF for invalid lanes
            const unsigned kmin = wave_min_u32(key);
            const unsigned long long tied = __ballot(key == kmin);
            const int winlane = __builtin_ctzll(tied);
            const unsigned cand = (qq == winlane) ? 0xFFFFFFFFu : key;
            const unsigned k2   = wave_min_u32(cand);      // 2nd-min (dups kept)
            if (qq == 0) {
                const size_t idx = ((size_t)b * NT + t) * NTILE + tix;
                pm1[idx] = key_f32(kmin); pm2[idx] = key_f32(k2);
                pmj[idx] = q0 + winlane;
            }
        }
    }
    __syncthreads();      // all waves' global stores drained before release
    if (tid == 0)
        __hip_atomic_store(&done[b * 16 + tix], MAGIC, __ATOMIC_RELEASE, __HIP_MEMORY_SCOPE_AGENT);
    if (tix != 0) return;

    // ====== Handoff: threads 0..9 each acquire-spin on one tile slot =======
    if (tid < NTILE) {
        int spins = 0;
        while (__hip_atomic_load(&done[b * 16 + tid], __ATOMIC_ACQUIRE, __HIP_MEMORY_SCOPE_AGENT) != MAGIC) {
            __builtin_amdgcn_s_sleep(8);
            if (++spins > SPINCAP) break;   // hang guard (fails loudly)
        }
    }
    __syncthreads();

    // ---- init solver state ----
    for (int c = tid; c < QQ; c += NTHR) { pA[c] = -1; verA[c] = 0; vA[c] = 0.0; colrow[c] = 0x7fffffff; }
    if (tid < NT) { assigned[tid] = 0; bidver[tid] = 0; cslot[tid] = -1; }
    if (tid == 0) ncache = 0;
    __syncthreads();

    // ---- combine tile partials -> full-row bids (R6 verbatim) ----
    if (tid < NT) {
        const int t = tid;
        const float* p1 = pm1 + ((size_t)b * NT + t) * NTILE;
        const float* p2 = pm2 + ((size_t)b * NT + t) * NTILE;
        const int*   pj = pmj + ((size_t)b * NT + t) * NTILE;
        float m1 = INFINITY, m2 = INFINITY; int j1 = QQ;
        for (int k = 0; k < NTILE; ++k) {       // ascending => first-occurrence
            const float a1 = p1[k], a2 = p2[k];
            const int   aj = pj[k];
            if (a1 < m1) { m2 = fminf(m1, a2); m1 = a1; j1 = aj; }
            else         { m2 = fminf(m2, a1); }
        }
        bidm1[t] = (double)m1; bidm2[t] = (double)m2; bidj[t] = j1;
        u[t] = (double)m1;      // feasible: keys only increase afterwards
    }
    __syncthreads();

    // fetch C row i into float dst[SLOTS]; serve from / fill LDS row cache
#define FETCH_ROW(dst, i)                                                      \
    do {                                                                       \
        const int _cs = cslot[i];                                              \
        if (_cs >= 0) {                                                        \
            _Pragma("unroll")                                                  \
            for (int k = 0; k < SLOTS; ++k) {                                  \
                const int c = qq + 64 * k;                                     \
                dst[k] = (c < QQ) ? cacheF[_cs * QQ + c] : 0.f;                \
            }                                                                  \
        } else {                                                               \
            const float* _rp = C + (size_t)(i) * QQ;                           \
            _Pragma("unroll")                                                  \
            for (int k = 0; k < SLOTS; ++k) {                                  \
                const int c = qq + 64 * k;                                     \
                dst[k] = (c < QQ) ? _rp[c] : 0.f;                              \
            }                                                                  \
            int _slot = 0;                                                     \
            if (qq == 0) _slot = atomicAdd(&ncache, 1);                        \
            _slot = __shfl(_slot, 0);                                          \
            if (_slot < NCAP) {                                                \
                _Pragma("unroll")                                              \
                for (int k = 0; k < SLOTS; ++k) {                              \
                    const int c = qq + 64 * k;                                 \
                    if (c < QQ) cacheF[_slot * QQ + c] = dst[k];               \
                }                                                              \
                if (qq == 0) cslot[i] = _slot;                                 \
            }                                                                  \
        }                                                                      \
    } while (0)

    // ================= Jacobi parallel auction =============================
    // R17: round-versioned colrow (no clear; fresh rounds have smaller keys),
    // fixed row->wave ownership (i%NWAVE) so cache fills are wave-private,
    // __syncthreads_count termination. Bid/resolve math unchanged.
    int prev_np = 0x7fffffff, stall = 0;
    for (int round = 0; round < MAXROUNDS; ++round) {
        const int rkey = (MAXROUNDS - round) << 7;
        if (tid < NT && !assigned[tid]) {
            const int j = bidj[tid];
            if (bidver[tid] == verA[j]) atomicMin(&colrow[j], rkey | tid);
        }
        __syncthreads();
        if (tid < NT && !assigned[tid]) {
            const int i = tid, j = bidj[i];
            if (bidver[i] == verA[j] && colrow[j] == (rkey | i)) {
                const double m1 = bidm1[i], m2 = bidm2[i];
                const int prev = pA[j];
                pA[j] = i;
                verA[j] = verA[j] + 1;
                vA[j] -= (m2 - m1);          // v only decreases (diff >= 0)
                u[i] = m2;
                assigned[i] = 1;
                if (prev >= 0) assigned[prev] = 0;
            }
        }
        __syncthreads();
        const int np = __syncthreads_count(tid < NT && !assigned[tid]);
        if (np == 0) break;
        if (np >= prev_np) { if (++stall >= STALLCAP) break; }
        else               { stall = 0; }
        prev_np = np;
        for (int i = wv; i < NT; i += NWAVE) {
            if (assigned[i]) continue;
            float rowv[SLOTS];
            FETCH_ROW(rowv, i);
            double m1 = INFINITY, m2 = INFINITY; int j1 = QQ;
            #pragma unroll
            for (int k = 0; k < SLOTS; ++k) {
                const int c = qq + 64 * k;
                if (c < QQ) {
                    const double key = (double)rowv[k] - vA[c];
                    if (key < m1)      { m2 = m1; m1 = key; j1 = c; }
                    else if (key < m2) { m2 = key; }
                }
            }
            const unsigned long long k1 = f64_key(m1);
            const unsigned long long kminv = wave_min_u64(k1);
            const unsigned long long tied = __ballot(k1 == kminv);
            const int winlane = __builtin_ctzll(tied);
            // global 2nd-min = min over (winner's m2, everyone else's m1)
            const unsigned long long c2 = (qq == winlane) ? f64_key(m2) : k1;
            const unsigned long long k2minv = wave_min_u64(c2);
            const int jwin = __shfl(j1, winlane);
            if (qq == 0) {
                bidm1[i] = key_f64(kminv); bidm2[i] = key_f64(k2minv); bidj[i] = jwin;
                bidver[i] = verA[jwin];
                u[i] = key_f64(kminv);       // feasible forever (v only dec.)
            }
        }
        __syncthreads();
    }

    if (wv != 0) return;   // ============ wave 0 only below; no barriers ====
    const int lane = qq;

    // collect drained rows (uniform control flow)
    int nd = 0;
    for (int i = 0; i < NT; ++i) {
        if (!assigned[i]) { if (lane == 0) djkA[nd] = i; ++nd; }
    }

    double v_[SLOTS], minv_[SLOTS];
    int p_[SLOTS];
    #pragma unroll
    for (int k = 0; k < SLOTS; ++k) {
        const int c = lane + 64 * k;
        v_[k] = (c < QQ) ? vA[c] : 0.0;
        p_[k] = (c < QQ) ? pA[c] : -1;
    }

    // ================= Dijkstra SAP (exact) ================================
    float rowv[SLOTS];
    for (int ii = 0; ii < nd; ++ii) {
        const int i = djkA[ii];
        #pragma unroll
        for (int k = 0; k < SLOTS; ++k) minv_[k] = INFINITY;
        unsigned usedm = 0;
        int j0 = -1;
        double ui0 = u[i];
        FETCH_ROW(rowv, i);
        int j1, i1;

        for (;;) {
            if (j0 >= 0 && (j0 & 63) == lane) usedm |= 1u << (j0 >> 6);

            double bestv = INFINITY; int bestc = QQ;
            #pragma unroll
            for (int k = 0; k < SLOTS; ++k) {
                const int c = lane + 64 * k;
                if (c < QQ && !((usedm >> k) & 1u)) {
                    const double cur = ((double)rowv[k] - ui0) - v_[k];
                    if (cur < minv_[k]) { minv_[k] = cur; wayA[c] = j0; }
                    if (minv_[k] < bestv) { bestv = minv_[k]; bestc = c; }
                }
            }
            const unsigned long long kb = f64_key(bestv);
            const unsigned long long kminv = wave_min_u64(kb);
            const unsigned long long tied = __ballot(kb == kminv);
            const int winlane = __builtin_ctzll(tied);
            const double delta = key_f64(kminv);
            j1 = __shfl(bestc, winlane);

            {   // i1 = p[j1] via register select + shuffle
                const int slot = j1 >> 6, lj = j1 & 63;
                int myp = p_[0];
                #pragma unroll
                for (int k = 1; k < SLOTS; ++k) if (slot == k) myp = p_[k];
                i1 = __shfl(myp, lj);
            }

            double ui_next = 0.0;
            float rown[SLOTS];
            if (i1 >= 0) {      // prefetch next row (not in tree -> u stable)
                ui_next = u[i1];
                FETCH_ROW(rown, i1);
            }

            #pragma unroll
            for (int k = 0; k < SLOTS; ++k) {
                const int c = lane + 64 * k;
                if (c < QQ) {
                    if ((usedm >> k) & 1u) { v_[k] -= delta; u[p_[k]] += delta; }
                    else                     minv_[k] -= delta;
                }
            }
            if (lane == 0) u[i] += delta;

            j0 = j1;
            if (i1 < 0) break;
            ui0 = ui_next;
            #pragma unroll
            for (int k = 0; k < SLOTS; ++k) rowv[k] = rown[k];
        }

        if (lane == 0) {        // augment along way chain
            int jj = j1;
            while (jj >= 0) {
                const int pr = wayA[jj];
                pA[jj] = (pr < 0) ? i : pA[pr];
                jj = pr;
            }
        }
        #pragma unroll
        for (int k = 0; k < SLOTS; ++k) {
            const int c = lane + 64 * k;
            p_[k] = (c < QQ) ? pA[c] : -1;
        }
    }

    // ---- emit in increasing query order (== reference's stable argsort) ----
    #pragma unroll
    for (int k = 0; k < SLOTS; ++k) {
        const int c = lane + 64 * k;
        if (c < QQ) { const int t = pA[c]; if (t >= 0) c4r[t] = c; }
    }
    for (int t = lane; t < NT; t += 64) {
        const int c = c4r[t];
        int rank = 0;
        for (int t2 = 0; t2 < NT; ++t2) rank += (c4r[t2] < c) ? 1 : 0;
        rows_out[b * NT + rank] = c;
        cols_out[b * NT + rank] = t;
    }
}

extern "C" void kernel_launch(void* const* d_in, const int* in_sizes, int n_in,
                              void* d_out, int out_size, void* d_ws, size_t ws_size,
                              hipStream_t stream) {
    (void)in_sizes; (void)n_in; (void)out_size; (void)ws_size;
    const float* logits  = (const float*)d_in[0];
    const float* pboxes  = (const float*)d_in[1];
    const int*   tlabels = (const int*)d_in[2];
    const float* tboxes  = (const float*)d_in[3];
    float* cost = (float*)d_ws;                          // 12,288,000 B
    float* pm1  = cost + (size_t)BB * NT * QQ;           // +204,800 B
    float* pm2  = pm1  + (size_t)BB * NT * NTILE;        // +204,800 B
    int*   pmj  = (int*)(pm2 + (size_t)BB * NT * NTILE); // +204,800 B
    int*   done = pmj + (size_t)BB * NT * NTILE;         // +4,096 B (B*16 slots)
    int*   out  = (int*)d_out;

    // no memset: per-slot MAGIC handshake needs no initialization
    matcher_kernel<<<dim3(BB * NTILE), NTHR, 0, stream>>>(
        logits, pboxes, tlabels, tboxes, cost, pm1, pm2, pmj, done,
        out, out + BB * NT);
}

// Round 5
// 119.789 us; speedup vs baseline: 1.0947x; 1.0947x over previous
//
#include <hip/hip_runtime.h>
#include <math.h>

#define BB 64
#define QQ 600
#define NT 80
#define NC 92
#define SLOTS 10     // ceil(600/64)
#define NTILE 10     // 64-query tiles per batch
#define NTHR 256
#define NWAVE 4
#define MAXROUNDS 16 // Jacobi auction cap
#define STALLCAP 3   // break auction after 3 rounds with no new assignment
#define SPINCAP (1 << 20)
#define MAGIC 0x5A17C0DE

// ---------------------------------------------------------------------------
// R19 = R16 tail VERBATIM (64us measured; plist-balanced auction rebids,
// colrow clear per round, direct global row loads — no LDS row cache) +
// R17's Phase A only (the piece R18's counters endorsed: VALUBusy 21->17.4
// while total regressed => Phase A helped, tail changes hurt).
// Phase A (R17): softmax stats 4-way parallel (wave w owns cols
// [w*23,w*23+23)); exp(x-m) written back into tile so the cost loop does an
// LDS read * inv_s instead of 20 expf/thread (expf/block 11k -> 5.9k).
// R18 lessons reverted: fixed row->wave rebid ownership (load imbalance on
// the ~6 contested rows) and LDS row cache (fill cost > reuse).
// ---------------------------------------------------------------------------

template <int CTRL>
__device__ __forceinline__ int dppi(int x) {
    return __builtin_amdgcn_update_dpp(x, x, CTRL, 0xF, 0xF, false);
}

// full-wave (64-lane) min of u32: 4x row_ror DPP (VALU) + xor16 swizzle + xor32
__device__ __forceinline__ unsigned wave_min_u32(unsigned x) {
    unsigned y;
    y = (unsigned)dppi<0x121>((int)x); x = x < y ? x : y;   // ror1
    y = (unsigned)dppi<0x122>((int)x); x = x < y ? x : y;   // ror2
    y = (unsigned)dppi<0x124>((int)x); x = x < y ? x : y;   // ror4
    y = (unsigned)dppi<0x128>((int)x); x = x < y ? x : y;   // ror8 -> row(16) min
    y = (unsigned)__builtin_amdgcn_ds_swizzle((int)x, 0x401F); x = x < y ? x : y; // xor16
    y = (unsigned)__shfl_xor((int)x, 32); x = x < y ? x : y;                      // xor32
    return x;
}

__device__ __forceinline__ unsigned long long u64min(unsigned long long a,
                                                     unsigned long long b) {
    return a < b ? a : b;
}

// full-wave min of u64 (two 32-bit halves per cross-lane move)
__device__ __forceinline__ unsigned long long wave_min_u64(unsigned long long x) {
    union U { unsigned long long v; int i[2]; };
    U c, o; c.v = x;
    o.i[0] = dppi<0x121>(c.i[0]); o.i[1] = dppi<0x121>(c.i[1]); c.v = u64min(c.v, o.v);
    o.i[0] = dppi<0x122>(c.i[0]); o.i[1] = dppi<0x122>(c.i[1]); c.v = u64min(c.v, o.v);
    o.i[0] = dppi<0x124>(c.i[0]); o.i[1] = dppi<0x124>(c.i[1]); c.v = u64min(c.v, o.v);
    o.i[0] = dppi<0x128>(c.i[0]); o.i[1] = dppi<0x128>(c.i[1]); c.v = u64min(c.v, o.v);
    o.i[0] = __builtin_amdgcn_ds_swizzle(c.i[0], 0x401F);
    o.i[1] = __builtin_amdgcn_ds_swizzle(c.i[1], 0x401F); c.v = u64min(c.v, o.v);
    o.i[0] = __shfl_xor(c.i[0], 32);
    o.i[1] = __shfl_xor(c.i[1], 32);                       c.v = u64min(c.v, o.v);
    return c.v;
}

// order-preserving bijections float<->u32, double<->u64 (no NaNs in data)
__device__ __forceinline__ unsigned f32_key(float f) {
    unsigned b = __float_as_uint(f);
    return b ^ ((unsigned)((int)b >> 31) | 0x80000000u);
}
__device__ __forceinline__ float key_f32(unsigned k) {
    unsigned b = (k & 0x80000000u) ? (k ^ 0x80000000u) : ~k;
    return __uint_as_float(b);
}
__device__ __forceinline__ unsigned long long f64_key(double d) {
    unsigned long long b = (unsigned long long)__double_as_longlong(d);
    return b ^ ((unsigned long long)((long long)b >> 63) | 0x8000000000000000ULL);
}
__device__ __forceinline__ double key_f64(unsigned long long k) {
    unsigned long long b = (k & 0x8000000000000000ULL) ? (k ^ 0x8000000000000000ULL) : ~k;
    return __longlong_as_double((long long)b);
}

__global__ __launch_bounds__(256) void matcher_kernel(
    const float* __restrict__ logits,   // (B,Q,NC)
    const float* __restrict__ pboxes,   // (B,Q,4)
    const int*   __restrict__ tlabels,  // (B,NT)
    const float* __restrict__ tboxes,   // (B,NT,4)
    float* __restrict__ cost,           // (B,NT,QQ) ws
    float* __restrict__ pm1,            // (B,NT,NTILE) ws
    float* __restrict__ pm2,            // (B,NT,NTILE) ws
    int*   __restrict__ pmj,            // (B,NT,NTILE) ws
    int*   __restrict__ done,           // (B*16) ws slots, NO init needed
    int* __restrict__ rows_out,         // (B,NT)
    int* __restrict__ cols_out)         // (B,NT)
{
    __shared__ float tile[64 * 93];
    __shared__ float s_pm[4 * 64], s_ps[4 * 64];
    __shared__ float s_tb[NT * 4];
    __shared__ int   s_tl[NT];
    // solver state (tix==0 block only)
    __shared__ double vA[QQ];
    __shared__ double u[NT];
    __shared__ double bidm1[NT], bidm2[NT];
    __shared__ int    bidj[NT], bidver[NT];
    __shared__ int    pA[QQ];
    __shared__ int    verA[QQ];
    __shared__ int    colrow[QQ];
    __shared__ int    assigned[NT];
    __shared__ int    plist[NT];
    __shared__ int    pcnt;
    __shared__ int    wayA[QQ];
    __shared__ int    c4r[NT];
    __shared__ int    djkA[NT];

    const int g   = blockIdx.x;
    const int b   = g / NTILE;
    const int tix = g % NTILE;
    const int tid = threadIdx.x;
    const int qq  = tid & 63;
    const int wv  = tid >> 6;           // 0..3
    const float* C = cost + (size_t)b * NT * QQ;

    // ================= Phase A: cost tile + partials =======================
    {
        const int q0 = tix * 64;
        const int nq = min(64, QQ - q0);   // 24 for the last tile
        const float* src = logits + ((size_t)b * QQ + q0) * NC;
        for (int idx = tid; idx < nq * NC; idx += 256) {
            const int r = idx / NC;
            tile[r * 93 + (idx - r * NC)] = src[idx];
        }
        for (int i = tid; i < NT * 4; i += 256) s_tb[i] = tboxes[b * NT * 4 + i];
        for (int i = tid; i < NT;     i += 256) s_tl[i] = tlabels[b * NT + i];
        __syncthreads();

        // R17 Phase-A stats: 4-way parallel; wave w owns cols [w*23, w*23+23).
        // Rows >= nq produce garbage stats (tile uninitialized) — never read.
        {
            const int c0 = wv * 23;
            const float* r = &tile[qq * 93];
            float pm = r[c0];
            #pragma unroll 11
            for (int c = 1; c < 23; ++c) pm = fmaxf(pm, r[c0 + c]);
            s_pm[wv * 64 + qq] = pm;
        }
        __syncthreads();
        {
            const int c0 = wv * 23;
            float* r = &tile[qq * 93];
            const float m = fmaxf(fmaxf(s_pm[qq], s_pm[64 + qq]),
                                  fmaxf(s_pm[128 + qq], s_pm[192 + qq]));
            float sum = 0.f;
            #pragma unroll 11
            for (int c = 0; c < 23; ++c) {
                const float e = expf(r[c0 + c] - m);
                r[c0 + c] = e;                  // exp written back into tile
                sum += e;
            }
            s_ps[wv * 64 + qq] = sum;
        }
        __syncthreads();

        const bool valid = qq < nq;
        float px1 = 0.f, py1 = 0.f, px2 = 0.f, py2 = 0.f, pa = 0.f, inv_s = 1.f;
        if (valid) {
            const float* pb = pboxes + ((size_t)b * QQ + q0 + qq) * 4;
            px1 = pb[0]; py1 = pb[1]; px2 = pb[2]; py2 = pb[3];
            pa  = (px2 - px1) * (py2 - py1);
            const float s = (s_ps[qq] + s_ps[64 + qq]) + (s_ps[128 + qq] + s_ps[192 + qq]);
            inv_s = 1.f / s;
        }
        float* crow = cost + (size_t)b * NT * QQ + q0 + qq;

        for (int tt = 0; tt < 20; ++tt) {
            const int t = wv * 20 + tt;
            float costv = INFINITY;
            if (valid) {
                const int lbl = s_tl[t];
                const float cc = -(tile[qq * 93 + lbl] * inv_s);  // exp precomputed
                const float tx1 = s_tb[t*4+0], ty1 = s_tb[t*4+1];
                const float tx2 = s_tb[t*4+2], ty2 = s_tb[t*4+3];
                const float cb = fabsf(px1-tx1) + fabsf(py1-ty1)
                               + fabsf(px2-tx2) + fabsf(py2-ty2);
                const float ta = (tx2 - tx1) * (ty2 - ty1);
                const float iw = fmaxf(fminf(px2, tx2) - fmaxf(px1, tx1), 0.f);
                const float ih = fmaxf(fminf(py2, ty2) - fmaxf(py1, ty1), 0.f);
                const float inter = iw * ih;
                const float uni   = pa + ta - inter;
                const float iou   = inter / uni;
                const float cw = fmaxf(fmaxf(px2, tx2) - fminf(px1, tx1), 0.f);
                const float ch = fmaxf(fmaxf(py2, ty2) - fminf(py1, ty1), 0.f);
                const float ac = cw * ch;
                const float giou = iou - (ac - uni) / ac;
                costv = (1.0f * cc + 5.0f * cb) + 2.0f * (-giou);
                crow[(size_t)t * QQ] = costv;
            }
            // DPP min-reduce on sortable keys + ballot argmin (R16-validated)
            const unsigned key  = f32_key(costv);          // INF for invalid lanes
            const unsigned kmin = wave_min_u32(key);
            const unsigned long long tied = __ballot(key == kmin);
            const int winlane = __builtin_ctzll(tied);
            const unsigned cand = (qq == winlane) ? 0xFFFFFFFFu : key;
            const unsigned k2   = wave_min_u32(cand);      // 2nd-min (dups kept)
            if (qq == 0) {
                const size_t idx = ((size_t)b * NT + t) * NTILE + tix;
                pm1[idx] = key_f32(kmin); pm2[idx] = key_f32(k2);
                pmj[idx] = q0 + winlane;
            }
        }
    }
    __syncthreads();      // all waves' global stores drained before release
    if (tid == 0)
        __hip_atomic_store(&done[b * 16 + tix], MAGIC, __ATOMIC_RELEASE, __HIP_MEMORY_SCOPE_AGENT);
    if (tix != 0) return;

    // ====== Handoff: threads 0..9 each acquire-spin on one tile slot =======
    if (tid < NTILE) {
        int spins = 0;
        while (__hip_atomic_load(&done[b * 16 + tid], __ATOMIC_ACQUIRE, __HIP_MEMORY_SCOPE_AGENT) != MAGIC) {
            __builtin_amdgcn_s_sleep(8);
            if (++spins > SPINCAP) break;   // hang guard (fails loudly)
        }
    }
    __syncthreads();

    // ---- init solver state ----
    for (int c = tid; c < QQ; c += NTHR) { pA[c] = -1; verA[c] = 0; vA[c] = 0.0; }
    if (tid < NT) { assigned[tid] = 0; bidver[tid] = 0; }
    __syncthreads();

    // ---- combine tile partials -> full-row bids (R6 verbatim) ----
    if (tid < NT) {
        const int t = tid;
        const float* p1 = pm1 + ((size_t)b * NT + t) * NTILE;
        const float* p2 = pm2 + ((size_t)b * NT + t) * NTILE;
        const int*   pj = pmj + ((size_t)b * NT + t) * NTILE;
        float m1 = INFINITY, m2 = INFINITY; int j1 = QQ;
        for (int k = 0; k < NTILE; ++k) {       // ascending => first-occurrence
            const float a1 = p1[k], a2 = p2[k];
            const int   aj = pj[k];
            if (a1 < m1) { m2 = fminf(m1, a2); m1 = a1; j1 = aj; }
            else         { m2 = fminf(m2, a1); }
        }
        bidm1[t] = (double)m1; bidm2[t] = (double)m2; bidj[t] = j1;
        u[t] = (double)m1;      // feasible: keys only increase afterwards
    }
    __syncthreads();

    // ================= Jacobi parallel auction (R16 verbatim) ==============
    int prev_np = 0x7fffffff, stall = 0;
    for (int round = 0; round < MAXROUNDS; ++round) {
        for (int c = tid; c < QQ; c += NTHR) colrow[c] = 0x7fffffff;
        if (tid == 0) pcnt = 0;
        __syncthreads();
        if (tid < NT && !assigned[tid]) {
            const int j = bidj[tid];
            if (bidver[tid] == verA[j]) atomicMin(&colrow[j], tid);
        }
        __syncthreads();
        if (tid < NT && !assigned[tid]) {
            const int i = tid, j = bidj[i];
            if (bidver[i] == verA[j] && colrow[j] == i) {
                const double m1 = bidm1[i], m2 = bidm2[i];
                const int prev = pA[j];
                pA[j] = i;
                verA[j] = verA[j] + 1;
                vA[j] -= (m2 - m1);          // v only decreases (diff >= 0)
                u[i] = m2;
                assigned[i] = 1;
                if (prev >= 0) assigned[prev] = 0;
            }
        }
        __syncthreads();
        if (tid < NT && !assigned[tid]) { const int k = atomicAdd(&pcnt, 1); plist[k] = tid; }
        __syncthreads();
        const int np = pcnt;
        if (np == 0) break;
        if (np >= prev_np) { if (++stall >= STALLCAP) break; }
        else               { stall = 0; }
        prev_np = np;
        for (int idx = wv; idx < np; idx += NWAVE) {
            const int i = plist[idx];
            const float* rp = C + (size_t)i * QQ;
            float rowv[SLOTS];
            #pragma unroll
            for (int k = 0; k < SLOTS; ++k) { const int c = qq + 64*k; rowv[k] = (c < QQ) ? rp[c] : 0.f; }
            double m1 = INFINITY, m2 = INFINITY; int j1 = QQ;
            #pragma unroll
            for (int k = 0; k < SLOTS; ++k) {
                const int c = qq + 64 * k;
                if (c < QQ) {
                    const double key = (double)rowv[k] - vA[c];
                    if (key < m1)      { m2 = m1; m1 = key; j1 = c; }
                    else if (key < m2) { m2 = key; }
                }
            }
            const unsigned long long k1 = f64_key(m1);
            const unsigned long long kminv = wave_min_u64(k1);
            const unsigned long long tied = __ballot(k1 == kminv);
            const int winlane = __builtin_ctzll(tied);
            // global 2nd-min = min over (winner's m2, everyone else's m1)
            const unsigned long long c2 = (qq == winlane) ? f64_key(m2) : k1;
            const unsigned long long k2minv = wave_min_u64(c2);
            const int jwin = __shfl(j1, winlane);
            if (qq == 0) {
                bidm1[i] = key_f64(kminv); bidm2[i] = key_f64(k2minv); bidj[i] = jwin;
                bidver[i] = verA[jwin];
                u[i] = key_f64(kminv);       // feasible forever (v only dec.)
            }
        }
        __syncthreads();
    }

    if (wv != 0) return;   // ============ wave 0 only below; no barriers ====
    const int lane = qq;

    // collect drained rows (uniform control flow)
    int nd = 0;
    for (int i = 0; i < NT; ++i) {
        if (!assigned[i]) { if (lane == 0) djkA[nd] = i; ++nd; }
    }

    double v_[SLOTS], minv_[SLOTS];
    int p_[SLOTS];
    #pragma unroll
    for (int k = 0; k < SLOTS; ++k) {
        const int c = lane + 64 * k;
        v_[k] = (c < QQ) ? vA[c] : 0.0;
        p_[k] = (c < QQ) ? pA[c] : -1;
    }

    // ================= Dijkstra SAP (exact, R16 verbatim) ==================
    float rowv[SLOTS];
    for (int ii = 0; ii < nd; ++ii) {
        const int i = djkA[ii];
        #pragma unroll
        for (int k = 0; k < SLOTS; ++k) minv_[k] = INFINITY;
        unsigned usedm = 0;
        int j0 = -1;
        double ui0 = u[i];
        {
            const float* rp = C + (size_t)i * QQ;
            #pragma unroll
            for (int k = 0; k < SLOTS; ++k) { const int c = lane + 64*k; rowv[k] = (c < QQ) ? rp[c] : 0.f; }
        }
        int j1, i1;

        for (;;) {
            if (j0 >= 0 && (j0 & 63) == lane) usedm |= 1u << (j0 >> 6);

            double bestv = INFINITY; int bestc = QQ;
            #pragma unroll
            for (int k = 0; k < SLOTS; ++k) {
                const int c = lane + 64 * k;
                if (c < QQ && !((usedm >> k) & 1u)) {
                    const double cur = ((double)rowv[k] - ui0) - v_[k];
                    if (cur < minv_[k]) { minv_[k] = cur; wayA[c] = j0; }
                    if (minv_[k] < bestv) { bestv = minv_[k]; bestc = c; }
                }
            }
            const unsigned long long kb = f64_key(bestv);
            const unsigned long long kminv = wave_min_u64(kb);
            const unsigned long long tied = __ballot(kb == kminv);
            const int winlane = __builtin_ctzll(tied);
            const double delta = key_f64(kminv);
            j1 = __shfl(bestc, winlane);

            {   // i1 = p[j1] via register select + shuffle
                const int slot = j1 >> 6, lj = j1 & 63;
                int myp = p_[0];
                #pragma unroll
                for (int k = 1; k < SLOTS; ++k) if (slot == k) myp = p_[k];
                i1 = __shfl(myp, lj);
            }

            double ui_next = 0.0;
            float rown[SLOTS];
            if (i1 >= 0) {      // prefetch next row (not in tree -> u stable)
                ui_next = u[i1];
                const float* rp = C + (size_t)i1 * QQ;
                #pragma unroll
                for (int k = 0; k < SLOTS; ++k) { const int c = lane + 64*k; rown[k] = (c < QQ) ? rp[c] : 0.f; }
            }

            #pragma unroll
            for (int k = 0; k < SLOTS; ++k) {
                const int c = lane + 64 * k;
                if (c < QQ) {
                    if ((usedm >> k) & 1u) { v_[k] -= delta; u[p_[k]] += delta; }
                    else                     minv_[k] -= delta;
                }
            }
            if (lane == 0) u[i] += delta;

            j0 = j1;
            if (i1 < 0) break;
            ui0 = ui_next;
            #pragma unroll
            for (int k = 0; k < SLOTS; ++k) rowv[k] = rown[k];
        }

        if (lane == 0) {        // augment along way chain
            int jj = j1;
            while (jj >= 0) {
                const int pr = wayA[jj];
                pA[jj] = (pr < 0) ? i : pA[pr];
                jj = pr;
            }
        }
        #pragma unroll
        for (int k = 0; k < SLOTS; ++k) {
            const int c = lane + 64 * k;
            p_[k] = (c < QQ) ? pA[c] : -1;
        }
    }

    // ---- emit in increasing query order (== reference's stable argsort) ----
    #pragma unroll
    for (int k = 0; k < SLOTS; ++k) {
        const int c = lane + 64 * k;
        if (c < QQ) { const int t = pA[c]; if (t >= 0) c4r[t] = c; }
    }
    for (int t = lane; t < NT; t += 64) {
        const int c = c4r[t];
        int rank = 0;
        for (int t2 = 0; t2 < NT; ++t2) rank += (c4r[t2] < c) ? 1 : 0;
        rows_out[b * NT + rank] = c;
        cols_out[b * NT + rank] = t;
    }
}

extern "C" void kernel_launch(void* const* d_in, const int* in_sizes, int n_in,
                              void* d_out, int out_size, void* d_ws, size_t ws_size,
                              hipStream_t stream) {
    (void)in_sizes; (void)n_in; (void)out_size; (void)ws_size;
    const float* logits  = (const float*)d_in[0];
    const float* pboxes  = (const float*)d_in[1];
    const int*   tlabels = (const int*)d_in[2];
    const float* tboxes  = (const float*)d_in[3];
    float* cost = (float*)d_ws;                          // 12,288,000 B
    float* pm1  = cost + (size_t)BB * NT * QQ;           // +204,800 B
    float* pm2  = pm1  + (size_t)BB * NT * NTILE;        // +204,800 B
    int*   pmj  = (int*)(pm2 + (size_t)BB * NT * NTILE); // +204,800 B
    int*   done = pmj + (size_t)BB * NT * NTILE;         // +4,096 B (B*16 slots)
    int*   out  = (int*)d_out;

    // no memset: per-slot MAGIC handshake needs no initialization
    matcher_kernel<<<dim3(BB * NTILE), NTHR, 0, stream>>>(
        logits, pboxes, tlabels, tboxes, cost, pm1, pm2, pmj, done,
        out, out + BB * NT);
}